// Round 2
// baseline (38873.672 us; speedup 1.0000x reference)
//
#include <hip/hip_runtime.h>
#include <cstdint>
#include <cstddef>

#define SEQ   8192
#define EMB   512
#define HID   2048
#define NCH   256
#define CAT   (EMB + HID)        // 2560
#define NBLK  256                // one block per CU
#define NTH   512                // 8 waves
#define JPW   8                  // hidden components per block (== waves)
#define KPJ   20                 // K chunks per lane: CAT / 128

__device__ __forceinline__ unsigned long long packpair(float v, unsigned tag) {
    return ((unsigned long long)tag << 32) | (unsigned long long)__float_as_uint(v);
}

// Pin a float2 into VGPRs: blocks rematerialization of the originating load
// (value flows through an opaque asm), so the one-time weight load cannot be
// sunk into the 8192-step loop.
#define PIN2(v) asm volatile("" : "+v"((v).x), "+v"((v).y))

__global__
__attribute__((amdgpu_flat_work_group_size(NTH, NTH)))
__attribute__((amdgpu_waves_per_eu(2, 2)))   // budget exactly 256 VGPR/wave
void lstm_persistent(const int* __restrict__ seq,
                     const float* __restrict__ h0,
                     const float* __restrict__ c0,
                     const float* __restrict__ emb,
                     const float* __restrict__ Wf, const float* __restrict__ bfv,
                     const float* __restrict__ Wi, const float* __restrict__ biv,
                     const float* __restrict__ Wo, const float* __restrict__ bov,
                     const float* __restrict__ Wc, const float* __restrict__ bcv,
                     const float* __restrict__ Wout, const float* __restrict__ boutv,
                     float* __restrict__ out,
                     unsigned long long* __restrict__ hbuf)   // [2][HID] tagged pairs
{
    const int cu  = blockIdx.x;          // 0..255
    const int tid = threadIdx.x;         // 0..511
    const int wv  = tid >> 6;            // wave 0..7
    const int ln  = tid & 63;
    const int j   = cu * JPW + wv;       // hidden index owned by this wave

    __shared__ float z_lds[CAT];
    __shared__ float wred[JPW];

    // ---- persistent weights in registers: lane ln holds k = q*128 + 2*ln + {0,1} ----
    float2 w0[KPJ], w1[KPJ], w2[KPJ], w3[KPJ];
    {
        const float* r0 = Wf + (size_t)j * CAT + ln * 2;
        const float* r1 = Wi + (size_t)j * CAT + ln * 2;
        const float* r2 = Wo + (size_t)j * CAT + ln * 2;
        const float* r3 = Wc + (size_t)j * CAT + ln * 2;
        #pragma unroll
        for (int q = 0; q < KPJ; ++q) {
            w0[q] = *(const float2*)(r0 + q * 128);
            w1[q] = *(const float2*)(r1 + q * 128);
            w2[q] = *(const float2*)(r2 + q * 128);
            w3[q] = *(const float2*)(r3 + q * 128);
        }
        #pragma unroll
        for (int q = 0; q < KPJ; ++q) {
            PIN2(w0[q]); PIN2(w1[q]); PIN2(w2[q]); PIN2(w3[q]);
        }
    }
    float4 ww = *(const float4*)(Wout + (size_t)cu * HID + tid * 4);
    asm volatile("" : "+v"(ww.x), "+v"(ww.y), "+v"(ww.z), "+v"(ww.w));
    const float b0 = bfv[j], b1 = biv[j], b2 = bov[j], b3 = bcv[j];
    const float bout_cu = boutv[cu];

    float c = c0[j];                      // only lane 0 of each wave updates/uses

    // publish h_0 with tag 1 into slot 0
    if (ln == 0) {
        __hip_atomic_store(&hbuf[j], packpair(h0[j], 1u),
                           __ATOMIC_RELAXED, __HIP_MEMORY_SCOPE_AGENT);
    }

    int budget = 1 << 22;                 // total spin budget: fail loud, not hung
    float hv0 = 0.f, hv1 = 0.f, hv2 = 0.f, hv3 = 0.f;

    for (int t = 0; t < SEQ; ++t) {
        // stage x_t into registers (independent of h -> overlaps the poll)
        float4 xv;
        if (tid < EMB / 4) {
            const int ch = seq[t];
            xv = *(const float4*)(emb + (size_t)ch * EMB + tid * 4);
        }

        // poll this thread's 4 components of h_t (tag t+1) in slot t&1
        {
            unsigned long long* p = hbuf + (size_t)(t & 1) * HID + tid * 4;
            const unsigned want = (unsigned)(t + 1);
            unsigned long long v0, v1, v2, v3;
            while (true) {
                v0 = __hip_atomic_load(p + 0, __ATOMIC_RELAXED, __HIP_MEMORY_SCOPE_AGENT);
                v1 = __hip_atomic_load(p + 1, __ATOMIC_RELAXED, __HIP_MEMORY_SCOPE_AGENT);
                v2 = __hip_atomic_load(p + 2, __ATOMIC_RELAXED, __HIP_MEMORY_SCOPE_AGENT);
                v3 = __hip_atomic_load(p + 3, __ATOMIC_RELAXED, __HIP_MEMORY_SCOPE_AGENT);
                if ((unsigned)(v0 >> 32) == want && (unsigned)(v1 >> 32) == want &&
                    (unsigned)(v2 >> 32) == want && (unsigned)(v3 >> 32) == want) break;
                if (--budget < 0) break;
                __builtin_amdgcn_s_sleep(1);
            }
            hv0 = __uint_as_float((unsigned)v0);
            hv1 = __uint_as_float((unsigned)v1);
            hv2 = __uint_as_float((unsigned)v2);
            hv3 = __uint_as_float((unsigned)v3);
        }
        if (tid < EMB / 4) *(float4*)&z_lds[tid * 4] = xv;
        *(float4*)&z_lds[EMB + tid * 4] = make_float4(hv0, hv1, hv2, hv3);
        __syncthreads();

        // 4 gate-row dots over z = [x ; h]   (each wave covers full K)
        float a0 = 0.f, a1 = 0.f, a2 = 0.f, a3 = 0.f;
        #pragma unroll
        for (int q = 0; q < KPJ; ++q) {
            const float2 zv = *(const float2*)&z_lds[q * 128 + ln * 2];
            a0 = fmaf(w0[q].y, zv.y, fmaf(w0[q].x, zv.x, a0));
            a1 = fmaf(w1[q].y, zv.y, fmaf(w1[q].x, zv.x, a1));
            a2 = fmaf(w2[q].y, zv.y, fmaf(w2[q].x, zv.x, a2));
            a3 = fmaf(w3[q].y, zv.y, fmaf(w3[q].x, zv.x, a3));
        }
        // Wout partial for pred_{t-1} = Wout @ h_t (uses this thread's own 4 h values)
        float aw = fmaf(ww.x, hv0, fmaf(ww.y, hv1, fmaf(ww.z, hv2, ww.w * hv3)));

        #pragma unroll
        for (int m = 1; m < 64; m <<= 1) {
            a0 += __shfl_xor(a0, m, 64);
            a1 += __shfl_xor(a1, m, 64);
            a2 += __shfl_xor(a2, m, 64);
            a3 += __shfl_xor(a3, m, 64);
            aw += __shfl_xor(aw, m, 64);
        }

        if (ln == 0) {
            const float fg = 1.f / (1.f + __expf(-(a0 + b0)));
            const float ig = 1.f / (1.f + __expf(-(a1 + b1)));
            const float og = 1.f / (1.f + __expf(-(a2 + b2)));
            const float ct = tanhf(a3 + b3);
            c = fmaf(fg, c, ig * ct);
            const float hn = og * tanhf(c);
            // publish h_{t+1} (tag t+2) first: it's the inter-CU critical path
            __hip_atomic_store(&hbuf[(size_t)((t + 1) & 1) * HID + j],
                               packpair(hn, (unsigned)(t + 2)),
                               __ATOMIC_RELAXED, __HIP_MEMORY_SCOPE_AGENT);
            wred[wv] = aw;
        }
        __syncthreads();
        if (tid == NTH - 1 && t >= 1) {
            float p = bout_cu;
            #pragma unroll
            for (int q = 0; q < JPW; ++q) p += wred[q];
            out[(size_t)(t - 1) * NCH + cu] = p;
        }
    }

    // ---- epilogue: pred_{SEQ-1} needs h_SEQ (tag SEQ+1, slot SEQ&1 == 0) ----
    {
        unsigned long long* p = hbuf + (size_t)(SEQ & 1) * HID + tid * 4;
        const unsigned want = (unsigned)(SEQ + 1);
        unsigned long long v0, v1, v2, v3;
        while (true) {
            v0 = __hip_atomic_load(p + 0, __ATOMIC_RELAXED, __HIP_MEMORY_SCOPE_AGENT);
            v1 = __hip_atomic_load(p + 1, __ATOMIC_RELAXED, __HIP_MEMORY_SCOPE_AGENT);
            v2 = __hip_atomic_load(p + 2, __ATOMIC_RELAXED, __HIP_MEMORY_SCOPE_AGENT);
            v3 = __hip_atomic_load(p + 3, __ATOMIC_RELAXED, __HIP_MEMORY_SCOPE_AGENT);
            if ((unsigned)(v0 >> 32) == want && (unsigned)(v1 >> 32) == want &&
                (unsigned)(v2 >> 32) == want && (unsigned)(v3 >> 32) == want) break;
            if (--budget < 0) break;
            __builtin_amdgcn_s_sleep(1);
        }
        hv0 = __uint_as_float((unsigned)v0);
        hv1 = __uint_as_float((unsigned)v1);
        hv2 = __uint_as_float((unsigned)v2);
        hv3 = __uint_as_float((unsigned)v3);

        float aw = fmaf(ww.x, hv0, fmaf(ww.y, hv1, fmaf(ww.z, hv2, ww.w * hv3)));
        #pragma unroll
        for (int m = 1; m < 64; m <<= 1) aw += __shfl_xor(aw, m, 64);
        if (ln == 0) wred[wv] = aw;
        __syncthreads();
        if (tid == NTH - 1) {
            float p2 = bout_cu;
            #pragma unroll
            for (int q = 0; q < JPW; ++q) p2 += wred[q];
            out[(size_t)(SEQ - 1) * NCH + cu] = p2;
        }
        // final hidden state (any block has it; block 0 writes)
        if (cu == 0) {
            *(float4*)&out[(size_t)SEQ * NCH + tid * 4] =
                make_float4(hv0, hv1, hv2, hv3);
        }
        // final cell state (owned per wave lane 0)
        if (ln == 0) out[(size_t)SEQ * NCH + HID + j] = c;
    }
}

extern "C" void kernel_launch(void* const* d_in, const int* in_sizes, int n_in,
                              void* d_out, int out_size, void* d_ws, size_t ws_size,
                              hipStream_t stream)
{
    const int*   seq  = (const int*)  d_in[0];
    const float* h0   = (const float*)d_in[1];
    const float* c0   = (const float*)d_in[2];
    const float* emb  = (const float*)d_in[3];
    const float* Wf   = (const float*)d_in[4];
    const float* bf_  = (const float*)d_in[5];
    const float* Wi   = (const float*)d_in[6];
    const float* bi_  = (const float*)d_in[7];
    const float* Wo   = (const float*)d_in[8];
    const float* bo_  = (const float*)d_in[9];
    const float* Wc   = (const float*)d_in[10];
    const float* bc_  = (const float*)d_in[11];
    const float* Wout = (const float*)d_in[12];
    const float* bout = (const float*)d_in[13];
    float* out = (float*)d_out;
    unsigned long long* hbuf = (unsigned long long*)d_ws;  // 32 KB used

    void* args[] = { (void*)&seq, (void*)&h0, (void*)&c0, (void*)&emb,
                     (void*)&Wf, (void*)&bf_, (void*)&Wi, (void*)&bi_,
                     (void*)&Wo, (void*)&bo_, (void*)&Wc, (void*)&bc_,
                     (void*)&Wout, (void*)&bout, (void*)&out, (void*)&hbuf };

    hipError_t e = hipLaunchCooperativeKernel((void*)lstm_persistent,
                                              dim3(NBLK), dim3(NTH),
                                              args, 0, stream);
    if (e != hipSuccess) {
        lstm_persistent<<<dim3(NBLK), dim3(NTH), 0, stream>>>(
            seq, h0, c0, emb, Wf, bf_, Wi, bi_, Wo, bo_, Wc, bc_, Wout, bout,
            out, hbuf);
    }
}

// Round 4
// 26937.622 us; speedup vs baseline: 1.4431x; 1.4431x over previous
//
#include <hip/hip_runtime.h>
#include <cstdint>
#include <cstddef>

#define SEQ   8192
#define EMB   512
#define HID   2048
#define NCH   256
#define CAT   (EMB + HID)        // 2560
#define NBLK  256                // one block per CU
#define NTH   1024               // 16 waves
#define KQ    5                  // float4 chunks per lane per gate: 1280/64/4

__device__ __forceinline__ unsigned long long packpair(float v, unsigned tag) {
    return ((unsigned long long)tag << 32) | (unsigned long long)__float_as_uint(v);
}

#define PIN4(v) asm volatile("" : "+v"((v).x), "+v"((v).y), "+v"((v).z), "+v"((v).w))

// Wave sum via DPP row_shr (VALU-only, no LDS port): after the 1/2/4/8 chain
// the 16-lane row sums are in lanes 15/31/47/63 (row_shr moves data to HIGHER
// lanes); the two xor-shuffles then make lanes {15,31,47,63} hold the full
// 64-lane sum. Valid at lane 63 (use that).
#define DPP_ADD(x, ctrl) \
    x += __int_as_float(__builtin_amdgcn_update_dpp(0, __float_as_int(x), ctrl, 0xF, 0xF, true))

__device__ __forceinline__ float wave_sum(float x) {
    DPP_ADD(x, 0x111);   // row_shr:1
    DPP_ADD(x, 0x112);   // row_shr:2
    DPP_ADD(x, 0x114);   // row_shr:4
    DPP_ADD(x, 0x118);   // row_shr:8  -> lanes {15,31,47,63} hold row sums
    x += __shfl_xor(x, 16, 64);
    x += __shfl_xor(x, 32, 64);
    return x;            // valid at lanes {15,31,47,63}; consumers use lane 63
}

__global__
__attribute__((amdgpu_flat_work_group_size(NTH, NTH)))
__attribute__((amdgpu_waves_per_eu(4, 4)))   // 16 waves/CU: budget 128 VGPR/lane
void lstm_persistent(const int* __restrict__ seq,
                     const float* __restrict__ h0,
                     const float* __restrict__ c0,
                     const float* __restrict__ emb,
                     const float* __restrict__ Wf, const float* __restrict__ bfv,
                     const float* __restrict__ Wi, const float* __restrict__ biv,
                     const float* __restrict__ Wo, const float* __restrict__ bov,
                     const float* __restrict__ Wc, const float* __restrict__ bcv,
                     const float* __restrict__ Wout, const float* __restrict__ boutv,
                     float* __restrict__ out,
                     unsigned long long* __restrict__ hbuf)   // [2][HID] tagged pairs
{
    const int cu  = blockIdx.x;           // 0..255
    const int tid = threadIdx.x;          // 0..1023
    const int wv  = tid >> 6;             // wave 0..15
    const int ln  = tid & 63;
    const int jloc = wv >> 1;             // 0..7
    const int half = wv & 1;              // K-half
    const int j   = cu * 8 + jloc;        // gate-row owned by this wave
    const int base = half * 1280;         // K offset of this wave's half

    __shared__ float  z_lds[CAT];
    __shared__ float4 part4[16];          // per-wave 4-gate partials
    __shared__ float  wred[16];           // per-wave Wout partials

    // ---- persistent weights: 80 floats/lane (fits under the 128-VGPR budget) ----
    float4 w0[KQ], w1[KQ], w2[KQ], w3[KQ];
    {
        const size_t ro = (size_t)j * CAT + base + 4 * ln;
        #pragma unroll
        for (int q = 0; q < KQ; ++q) {
            w0[q] = *(const float4*)(Wf + ro + q * 256);
            w1[q] = *(const float4*)(Wi + ro + q * 256);
            w2[q] = *(const float4*)(Wo + ro + q * 256);
            w3[q] = *(const float4*)(Wc + ro + q * 256);
        }
        #pragma unroll
        for (int q = 0; q < KQ; ++q) { PIN4(w0[q]); PIN4(w1[q]); PIN4(w2[q]); PIN4(w3[q]); }
    }
    float2 ww = *(const float2*)(Wout + (size_t)cu * HID + 2 * tid);
    const float bout_cu = boutv[cu];

    // combiner state (threads 0..7 own j = cu*8+tid)
    float b0 = 0.f, b1 = 0.f, b2 = 0.f, b3 = 0.f, c = 0.f;
    if (tid < 8) {
        const int jm = cu * 8 + tid;
        b0 = bfv[jm]; b1 = biv[jm]; b2 = bov[jm]; b3 = bcv[jm];
        c = c0[jm];
        __hip_atomic_store(&hbuf[jm], packpair(h0[jm], 1u),
                           __ATOMIC_RELAXED, __HIP_MEMORY_SCOPE_AGENT);
    }

    int budget = 1 << 22;                 // loud-fail spin budget
    float h0v = 0.f, h1v = 0.f;

    for (int t = 0; t < SEQ; ++t) {
        // issue x_t load early (overlaps the poll)
        float4 xv;
        if (tid < EMB / 4) {
            xv = *(const float4*)(emb + (size_t)seq[t] * EMB + tid * 4);
        }

        // poll own 2 components of h_t (tag t+1) in slot t&1
        {
            unsigned long long* p = hbuf + (size_t)(t & 1) * HID + 2 * tid;
            const unsigned want = (unsigned)(t + 1);
            unsigned long long v0, v1;
            while (true) {
                v0 = __hip_atomic_load(p + 0, __ATOMIC_RELAXED, __HIP_MEMORY_SCOPE_AGENT);
                v1 = __hip_atomic_load(p + 1, __ATOMIC_RELAXED, __HIP_MEMORY_SCOPE_AGENT);
                if ((unsigned)(v0 >> 32) == want && (unsigned)(v1 >> 32) == want) break;
                if (--budget < 0) break;
                __builtin_amdgcn_s_sleep(1);
            }
            h0v = __uint_as_float((unsigned)v0);
            h1v = __uint_as_float((unsigned)v1);
        }
        if (tid < EMB / 4) *(float4*)&z_lds[tid * 4] = xv;
        *(float2*)&z_lds[EMB + 2 * tid] = make_float2(h0v, h1v);
        __syncthreads();

        // 4 gate dots over this wave's K-half (z loaded once, reused by 4 gates)
        float a0 = 0.f, a1 = 0.f, a2 = 0.f, a3 = 0.f;
        #pragma unroll
        for (int q = 0; q < KQ; ++q) {
            const float4 zv = *(const float4*)&z_lds[base + q * 256 + 4 * ln];
            a0 = fmaf(w0[q].x, zv.x, a0); a0 = fmaf(w0[q].y, zv.y, a0);
            a0 = fmaf(w0[q].z, zv.z, a0); a0 = fmaf(w0[q].w, zv.w, a0);
            a1 = fmaf(w1[q].x, zv.x, a1); a1 = fmaf(w1[q].y, zv.y, a1);
            a1 = fmaf(w1[q].z, zv.z, a1); a1 = fmaf(w1[q].w, zv.w, a1);
            a2 = fmaf(w2[q].x, zv.x, a2); a2 = fmaf(w2[q].y, zv.y, a2);
            a2 = fmaf(w2[q].z, zv.z, a2); a2 = fmaf(w2[q].w, zv.w, a2);
            a3 = fmaf(w3[q].x, zv.x, a3); a3 = fmaf(w3[q].y, zv.y, a3);
            a3 = fmaf(w3[q].z, zv.z, a3); a3 = fmaf(w3[q].w, zv.w, a3);
        }
        float aw = fmaf(ww.x, h0v, ww.y * h1v);   // Wout partial (pred_{t-1})

        a0 = wave_sum(a0); a1 = wave_sum(a1);
        a2 = wave_sum(a2); a3 = wave_sum(a3);
        aw = wave_sum(aw);

        if (ln == 63) { part4[wv] = make_float4(a0, a1, a2, a3); wred[wv] = aw; }
        __syncthreads();

        if (tid < 8) {
            const float4 pa = part4[2 * tid], pb = part4[2 * tid + 1];
            const float gf = 1.f / (1.f + __expf(-(pa.x + pb.x + b0)));
            const float gi = 1.f / (1.f + __expf(-(pa.y + pb.y + b1)));
            const float go = 1.f / (1.f + __expf(-(pa.z + pb.z + b2)));
            const float ct = tanhf(pa.w + pb.w + b3);
            c = fmaf(gf, c, gi * ct);
            const float hn = go * tanhf(c);
            __hip_atomic_store(&hbuf[(size_t)((t + 1) & 1) * HID + cu * 8 + tid],
                               packpair(hn, (unsigned)(t + 2)),
                               __ATOMIC_RELAXED, __HIP_MEMORY_SCOPE_AGENT);
        } else if (tid == 8 && t >= 1) {
            float s = bout_cu;
            #pragma unroll
            for (int q = 0; q < 16; ++q) s += wred[q];
            out[(size_t)(t - 1) * NCH + cu] = s;
        }
    }

    // ---- epilogue: pred_{SEQ-1} = Wout @ h_SEQ (tag SEQ+1, slot 0) ----
    {
        unsigned long long* p = hbuf + (size_t)(SEQ & 1) * HID + 2 * tid;
        const unsigned want = (unsigned)(SEQ + 1);
        unsigned long long v0, v1;
        while (true) {
            v0 = __hip_atomic_load(p + 0, __ATOMIC_RELAXED, __HIP_MEMORY_SCOPE_AGENT);
            v1 = __hip_atomic_load(p + 1, __ATOMIC_RELAXED, __HIP_MEMORY_SCOPE_AGENT);
            if ((unsigned)(v0 >> 32) == want && (unsigned)(v1 >> 32) == want) break;
            if (--budget < 0) break;
            __builtin_amdgcn_s_sleep(1);
        }
        h0v = __uint_as_float((unsigned)v0);
        h1v = __uint_as_float((unsigned)v1);

        float aw = fmaf(ww.x, h0v, ww.y * h1v);
        aw = wave_sum(aw);
        if (ln == 63) wred[wv] = aw;
        __syncthreads();
        if (tid == 8) {
            float s = bout_cu;
            #pragma unroll
            for (int q = 0; q < 16; ++q) s += wred[q];
            out[(size_t)(SEQ - 1) * NCH + cu] = s;
        }
        // final hidden state
        if (cu == 0) {
            *(float2*)&out[(size_t)SEQ * NCH + 2 * tid] = make_float2(h0v, h1v);
        }
        // final cell state
        if (tid < 8) out[(size_t)SEQ * NCH + HID + cu * 8 + tid] = c;
    }
}

extern "C" void kernel_launch(void* const* d_in, const int* in_sizes, int n_in,
                              void* d_out, int out_size, void* d_ws, size_t ws_size,
                              hipStream_t stream)
{
    const int*   seq  = (const int*)  d_in[0];
    const float* h0   = (const float*)d_in[1];
    const float* c0   = (const float*)d_in[2];
    const float* emb  = (const float*)d_in[3];
    const float* Wf   = (const float*)d_in[4];
    const float* bf_  = (const float*)d_in[5];
    const float* Wi   = (const float*)d_in[6];
    const float* bi_  = (const float*)d_in[7];
    const float* Wo   = (const float*)d_in[8];
    const float* bo_  = (const float*)d_in[9];
    const float* Wc   = (const float*)d_in[10];
    const float* bc_  = (const float*)d_in[11];
    const float* Wout = (const float*)d_in[12];
    const float* bout = (const float*)d_in[13];
    float* out = (float*)d_out;
    unsigned long long* hbuf = (unsigned long long*)d_ws;  // 32 KB used

    void* args[] = { (void*)&seq, (void*)&h0, (void*)&c0, (void*)&emb,
                     (void*)&Wf, (void*)&bf_, (void*)&Wi, (void*)&bi_,
                     (void*)&Wo, (void*)&bo_, (void*)&Wc, (void*)&bc_,
                     (void*)&Wout, (void*)&bout, (void*)&out, (void*)&hbuf };

    hipError_t e = hipLaunchCooperativeKernel((void*)lstm_persistent,
                                              dim3(NBLK), dim3(NTH),
                                              args, 0, stream);
    if (e != hipSuccess) {
        lstm_persistent<<<dim3(NBLK), dim3(NTH), 0, stream>>>(
            seq, h0, c0, emb, Wf, bf_, Wi, bi_, Wo, bo_, Wc, bc_, Wout, bout,
            out, hbuf);
    }
}